// Round 2
// baseline (203.350 us; speedup 1.0000x reference)
//
#include <hip/hip_runtime.h>
#include <stdint.h>

#define F 256
#define R 64                    // rows per tile
#define THREADS 256
#define GCH 32                  // g-rows per staged W chunk
#define NCH (F / GCH)           // 8 chunks
#define CH_SLOTS (GCH * F / 8)  // 1024 16B slots per chunk
#define TPB 4                   // row-tiles per block (software-pipeline depth)

typedef __attribute__((ext_vector_type(8))) short short8;
typedef __attribute__((ext_vector_type(4))) float floatx4;

// Single-instruction rotate: alignbit(x,x,32-d) == rotl(x,d).
__device__ __forceinline__ uint32_t rotl32(uint32_t x, int d) {
  return __builtin_amdgcn_alignbit(x, x, (uint32_t)(32 - d));
}

// Threefry keys + hoisted round-injection constants.
struct TFK { uint32_t k0, k1, k2, a1, a2, a3, a4, a5; };

__device__ __forceinline__ TFK mkkeys(uint32_t k0, uint32_t k1) {
  TFK K;
  K.k0 = k0; K.k1 = k1; K.k2 = k0 ^ k1 ^ 0x1BD11BDAu;
  K.a1 = K.k2 + 1u; K.a2 = k0 + 2u; K.a3 = k1 + 3u;
  K.a4 = K.k2 + 4u; K.a5 = k0 + 5u;
  return K;
}

// Single-chain threefry2x32 (20 rounds) — fold_in, once per tile.
__device__ __forceinline__ void tf_one(const TFK& K, uint32_t& x0, uint32_t& x1) {
  x0 += K.k0; x1 += K.k1;
#define TF1(r) x0 += x1; x1 = rotl32(x1, r); x1 ^= x0;
  TF1(13) TF1(15) TF1(26) TF1(6)   x0 += K.k1; x1 += K.a1;
  TF1(17) TF1(29) TF1(16) TF1(24)  x0 += K.k2; x1 += K.a2;
  TF1(13) TF1(15) TF1(26) TF1(6)   x0 += K.k0; x1 += K.a3;
  TF1(17) TF1(29) TF1(16) TF1(24)  x0 += K.k1; x1 += K.a4;
  TF1(13) TF1(15) TF1(26) TF1(6)   x0 += K.k2; x1 += K.a5;
#undef TF1
}

// Dual-chain threefry: counters i, i+1 in manually interleaved lockstep —
// 2 chains x 2-cyc issue exactly fills the 4-cyc dep latency per chain.
__device__ __forceinline__ void tf_pair(const TFK& K, uint32_t i,
                                        uint32_t& oa, uint32_t& ob) {
  uint32_t a0 = K.k0, a1 = K.k1 + i;
  uint32_t b0 = K.k0, b1 = K.k1 + i + 1u;
#define TF2(r)  a0 += a1; b0 += b1;                         \
                a1 = rotl32(a1, r); b1 = rotl32(b1, r);     \
                a1 ^= a0; b1 ^= b0;
#define INJ2(u, v) a0 += (u); b0 += (u); a1 += (v); b1 += (v);
  TF2(13) TF2(15) TF2(26) TF2(6)   INJ2(K.k1, K.a1)
  TF2(17) TF2(29) TF2(16) TF2(24)  INJ2(K.k2, K.a2)
  TF2(13) TF2(15) TF2(26) TF2(6)   INJ2(K.k0, K.a3)
  TF2(17) TF2(29) TF2(16) TF2(24)  INJ2(K.k1, K.a4)
  TF2(13) TF2(15) TF2(26) TF2(6)   INJ2(K.k2, K.a5)
#undef TF2
#undef INJ2
  oa = a0 ^ a1;
  ob = b0 ^ b1;
}

// Two features (counters i, i+1) -> packed bf16 pair. Bit-identical numerics:
// 2.3283064365386963e-8 IS 100*2^-32 (do NOT multiply by 100 again), RNE
// round, v_perm pack == (ulo>>16)|((uhi>>16)<<16).
__device__ __forceinline__ uint32_t featpack(const TFK& K, uint32_t i) {
  uint32_t xa, xb;
  tf_pair(K, i, xa, xb);
  uint32_t ulo = __float_as_uint((float)xa * 2.3283064365386963e-8f);
  uint32_t uhi = __float_as_uint((float)xb * 2.3283064365386963e-8f);
  ulo += 0x7FFFu + ((ulo >> 16) & 1u);
  uhi += 0x7FFFu + ((uhi >> 16) & 1u);
  return __builtin_amdgcn_perm(uhi, ulo, 0x07060302u);
}

// One A-fragment (8 features = 4 pairs) for features fb..fb+7.
__device__ __forceinline__ short8 quad(const TFK& K, uint32_t fb) {
  uint32_t w32[4];
  #pragma unroll
  for (int p = 0; p < 4; ++p) w32[p] = featpack(K, fb + 2u * p);
  union { uint32_t w[4]; short8 s; } u;
  u.w[0] = w32[0]; u.w[1] = w32[1]; u.w[2] = w32[2]; u.w[3] = w32[3];
  return u.s;
}

// fp32 -> bf16 RNE (conv kernel only)
__device__ __forceinline__ uint32_t f2bf(float f) {
  uint32_t u = __float_as_uint(f);
  u += 0x7FFFu + ((u >> 16) & 1u);
  return u >> 16;
}

__device__ __forceinline__ void gl_lds16(const void* gptr, void* lptr) {
  __builtin_amdgcn_global_load_lds(
      (const __attribute__((address_space(1))) uint32_t*)gptr,
      (__attribute__((address_space(3))) uint32_t*)lptr, 16, 0, 0);
}

// DMA one 16 KB W chunk into LDS (wave-uniform base + lane*16B, round-0 layout).
__device__ __forceinline__ void dma_chunk(const uint16_t* __restrict__ src,
                                          uint16_t* dst, int wave, int lane) {
  #pragma unroll
  for (int it = 0; it < CH_SLOTS / THREADS; ++it) {
    int sbase = it * THREADS + wave * 64;
    gl_lds16(src + (size_t)(sbase + lane) * 8, dst + (size_t)sbase * 8);
  }
}

// One-time: W fp32 -> bf16 TRANSPOSED into DMA slot order (unchanged).
// Slot s: chunk gt=s>>10, c=(s>>5)&31 (k-granule), g=s&31.
__global__ __launch_bounds__(256) void femb_conv(const float* __restrict__ W,
                                                 uint16_t* __restrict__ ws) {
  int s = blockIdx.x * 256 + threadIdx.x;   // 8192 slots
  int gt = s >> 10;
  int c = (s >> 5) & 31;
  int g = s & 31;
  const float4* src = (const float4*)(W + (size_t)(gt * GCH + g) * F + c * 8);
  float4 v0 = src[0], v1 = src[1];
  short8 o;
  o[0] = (short)f2bf(v0.x); o[1] = (short)f2bf(v0.y);
  o[2] = (short)f2bf(v0.z); o[3] = (short)f2bf(v0.w);
  o[4] = (short)f2bf(v1.x); o[5] = (short)f2bf(v1.y);
  o[6] = (short)f2bf(v1.z); o[7] = (short)f2bf(v1.w);
  *(short8*)(ws + (size_t)s * 8) = o;
}

// Software-pipelined main: each block owns TPB=4 consecutive 64-row tiles.
// Chunk gt of tile t computes afragNext[gt] (RNG for tile t+1) in the same
// barrier region as chunk gt's ds_read/MFMA/stores — memory latency drains
// under the RNG VALU burn instead of convoying after it. Tile t=-1 is a
// compute-free warm-up pass that builds tile 0's fragments with the SAME
// per-chunk code (no duplicated prologue; keeps I$ footprint ~1 tile body).
__global__ __launch_bounds__(THREADS, 2) void femb_main(
    const float* __restrict__ x, const uint16_t* __restrict__ Wbf,
    const float* __restrict__ bias, float* __restrict__ out) {
  __shared__ uint16_t sW[2][GCH * F];   // 2 x 16 KB double buffer

  const int tid  = threadIdx.x;
  const int lane = tid & 63;
  const int wave = tid >> 6;
  const int qd   = lane >> 4;
  const int l16  = lane & 15;
  const int tb0  = blockIdx.x * TPB;
  const int rl   = wave * 16 + l16;      // row-in-tile for x/fold_in

  const TFK K42 = mkkeys(0u, 42u);       // constant-folded

  // x for tile 0; consumed by the t=-1 warm-up's fold_in.
  float xn = x[(size_t)tb0 * R + rl];

  short8 afragC[8];                      // fragments for the tile being MFMA'd
  #pragma unroll 1
  for (int t = -1; t < TPB; ++t) {
    const bool hasNext  = (t + 1 < TPB);
    const bool doCompute = (t >= 0);

    // fold_in for tile t+1 (key from x bitcast); xn was loaded >=1 tile ago.
    TFK K2 = K42;
    if (hasNext) {
      uint32_t u0 = 0u, u1 = __float_as_uint(xn);
      tf_one(K42, u0, u1);
      K2 = mkkeys(u0, u1);
    }
    // prefetch x for tile t+2 (latency hidden under this tile's chunk loop)
    if (t + 2 < TPB) xn = x[(size_t)(tb0 + t + 2) * R + rl];

    const size_t growbase = doCompute
        ? ((size_t)(tb0 + t) * R + (size_t)(wave * 16 + qd * 4))
        : 0;

    short8 afragN[8];
    #pragma unroll
    for (int gt = 0; gt < NCH; ++gt) {
      __syncthreads();   // chunk gt DMA drained (vmcnt0) + prev buf reads done

      // keep the DMA pipeline full: stage chunk (gt+1)&7 into the other buf
      if (!((t == TPB - 1) && (gt == NCH - 1)))
        dma_chunk(Wbf + (size_t)((gt + 1) & 7) * CH_SLOTS * 8,
                  sW[(gt + 1) & 1], wave, lane);

      // RNG for tile t+1, fragment gt: features gt*32 + qd*8 + j
      if (hasNext)
        afragN[gt] = quad(K2, (uint32_t)(gt * 32 + qd * 8));

      if (doCompute) {
        const uint16_t* buf = sW[gt & 1];
        floatx4 acc[2];
        acc[0] = (floatx4){0.f, 0.f, 0.f, 0.f};
        acc[1] = (floatx4){0.f, 0.f, 0.f, 0.f};
        #pragma unroll
        for (int kt = 0; kt < 8; ++kt) {
          int c = kt * 4 + qd;
          #pragma unroll
          for (int n = 0; n < 2; ++n) {
            // slot = c*32 + n*16 + l16: 16 consecutive b128 per 16-lane group
            short8 b = *(const short8*)&buf[(size_t)(c * 32 + n * 16 + l16) * 8];
            acc[n] = __builtin_amdgcn_mfma_f32_16x16x32_bf16(afragC[kt], b,
                                                             acc[n], 0, 0, 0);
          }
        }
        // Epilogue: D[row=qd*4+reg][col=l16] (m89-verified layout).
        #pragma unroll
        for (int n = 0; n < 2; ++n) {
          int g = gt * GCH + n * 16 + l16;
          float bg = bias[g];
          #pragma unroll
          for (int reg = 0; reg < 4; ++reg)
            out[(growbase + reg) * F + g] = acc[n][reg] + bg;
        }
      }
    }

    if (hasNext) {
      #pragma unroll
      for (int i = 0; i < 8; ++i) afragC[i] = afragN[i];   // 32 movs/tile
    }
  }
}

extern "C" void kernel_launch(void* const* d_in, const int* in_sizes, int n_in,
                              void* d_out, int out_size, void* d_ws, size_t ws_size,
                              hipStream_t stream) {
  const float* x = (const float*)d_in[0];
  const float* W = (const float*)d_in[1];
  const float* b = (const float*)d_in[2];
  float* out = (float*)d_out;
  uint16_t* wsbf = (uint16_t*)d_ws;          // 128 KB of ws_size
  const int nrows = in_sizes[0];             // 131072
  const int blocks = nrows / (R * TPB);      // 512

  hipLaunchKernelGGL(femb_conv, dim3((F * F / 8) / 256), dim3(256), 0, stream, W, wsbf);
  hipLaunchKernelGGL(femb_main, dim3(blocks), dim3(THREADS), 0, stream,
                     x, wsbf, b, out);
}